// Round 6
// baseline (379.300 us; speedup 1.0000x reference)
//
#include <hip/hip_runtime.h>
#include <hip/hip_bf16.h>

// CausalDiscoveryModule: B=256, N=512, E=32, IN=512, K=10
// out[b,i,j] = gate_b * sigmoid(logit) on per-(b,i)-row top-10 of j, else 0
// logit = sum_e (c_b^2 * emb_i)[e] * emb_j[e]
//
// R6: branchless two-pass selection.
//  Pass 1: per-lane top-10 VALUES via v_med3_f32 sorted-insert (10 instr /
//          candidate, no divergence, no wave-max serialization). 4-way j-split
//          (med3 cost is per-candidate => split redundancy ~0), 8192 waves.
//  Merge:  exact global 10th value T = 10th of union of the 4 quarter lists
//          (rebuild from all 40 published values via med3).
//  Pass 2: recompute logits bit-identically; collect a >= T (~10/row) into
//          per-row LDS buffer (LDS atomics); final order via packed u64 key
//          (sortable(v)<<32 | (511-j)) == jax (value desc, index asc) ties.
//  Epilogue: cached zero-fill issued before the sort (overlap), vmcnt(0),
//          10 scattered dword stores/row merging in L2.

#define NUM_VARS 512
#define EMBED_DIM 32
#define IN_DIM 512
#define BATCH 256

typedef float nf4 __attribute__((ext_vector_type(4)));
typedef float f2 __attribute__((ext_vector_type(2)));

// ---------------- K1: context MLP -> w = c^2 [256][32], gate [256] ----------
__global__ __launch_bounds__(256) void cdm_k1(
    const float* __restrict__ ctx, const float* __restrict__ W1,
    const float* __restrict__ b1, const float* __restrict__ W2,
    const float* __restrict__ b2, const float* __restrict__ Wg,
    const float* __restrict__ bg, float* __restrict__ wws,
    float* __restrict__ gws) {
  const int bb = blockIdx.x;
  const int t = threadIdx.x;
  __shared__ float xs[512];
  __shared__ float psum[32][9];   // +1 pad
  __shared__ float hs[32];
  __shared__ float cs[32];
  const float* x = ctx + (bb << 9);
  xs[t] = x[t];
  xs[t + 256] = x[t + 256];
  __syncthreads();
  {
    const int e = t >> 3, part = t & 7;
    const float* wrow = W1 + e * 512 + part * 64;
    const float* xp = xs + part * 64;
    float a = 0.f;
#pragma unroll
    for (int m = 0; m < 64; ++m) a = fmaf(wrow[m], xp[m], a);
    psum[e][part] = a;
  }
  __syncthreads();
  if (t < 32) {
    float a = 0.f;
#pragma unroll
    for (int p = 0; p < 8; ++p) a += psum[t][p];
    hs[t] = fmaxf(a + b1[t], 0.f);
  }
  __syncthreads();
  if (t < 32) {
    const float* wrow = W2 + (t << 5);
    float a = 0.f;
#pragma unroll
    for (int k = 0; k < 32; ++k) a = fmaf(wrow[k], hs[k], a);
    float c = a + b2[t];
    cs[t] = c;
    wws[(bb << 5) + t] = c * c;
  }
  __syncthreads();
  if (t == 0) {
    float a = 0.f;
#pragma unroll
    for (int k = 0; k < 32; ++k) a = fmaf(Wg[k], cs[k], a);
    float g = a + bg[0];
    gws[bb] = 1.f / (1.f + __expf(-g));
  }
}

// med3 sorted-insert of value v into desc list hv[0..9] (values only, exact)
#define MED3_INSERT(hv, v)                                           \
  do {                                                               \
    _Pragma("unroll") for (int k = 9; k >= 1; --k)                   \
        hv[k] = __builtin_amdgcn_fmed3f((v), hv[k - 1], hv[k]);      \
    hv[0] = fmaxf(hv[0], (v));                                       \
  } while (0)

// u64-key shift insert, strict > (desc); key encodes (value desc, j asc)
#define KEY_INSERT(K, key)                                           \
  do {                                                               \
    _Pragma("unroll") for (int k = 9; k >= 1; --k) {                 \
      bool gk = (key) > K[k];                                        \
      bool gk1 = (key) > K[k - 1];                                   \
      K[k] = gk ? (gk1 ? K[k - 1] : (key)) : K[k];                   \
    }                                                                \
    K[0] = ((key) > K[0]) ? (key) : K[0];                            \
  } while (0)

// shared logit computation for a group of 4 consecutive j (identical
// expression tree in both passes -> bit-identical values)
__device__ __forceinline__ void compute4(const nf4* __restrict__ eb,
                                         const f2* sv2, int j0, float& a0,
                                         float& a1, float& a2, float& a3) {
  const nf4* p0 = eb + ((j0 + 0) << 3);
  const nf4* p1 = eb + ((j0 + 1) << 3);
  const nf4* p2 = eb + ((j0 + 2) << 3);
  const nf4* p3 = eb + ((j0 + 3) << 3);
  f2 c0 = {0.f, 0.f}, c1 = {0.f, 0.f}, c2 = {0.f, 0.f}, c3 = {0.f, 0.f};
#pragma unroll
  for (int q = 0; q < 8; ++q) {
    nf4 v0 = p0[q], v1 = p1[q], v2 = p2[q], v3 = p3[q];
    c0 += sv2[2 * q] * __builtin_shufflevector(v0, v0, 0, 1);
    c0 += sv2[2 * q + 1] * __builtin_shufflevector(v0, v0, 2, 3);
    c1 += sv2[2 * q] * __builtin_shufflevector(v1, v1, 0, 1);
    c1 += sv2[2 * q + 1] * __builtin_shufflevector(v1, v1, 2, 3);
    c2 += sv2[2 * q] * __builtin_shufflevector(v2, v2, 0, 1);
    c2 += sv2[2 * q + 1] * __builtin_shufflevector(v2, v2, 2, 3);
    c3 += sv2[2 * q] * __builtin_shufflevector(v3, v3, 0, 1);
    c3 += sv2[2 * q + 1] * __builtin_shufflevector(v3, v3, 2, 3);
  }
  a0 = c0.x + c0.y;
  a1 = c1.x + c1.y;
  a2 = c2.x + c2.y;
  a3 = c3.x + c3.y;
}

// ---------------- K2: 4-wave block per 64 rows; two-pass exact top-10 -------
__global__ __launch_bounds__(256, 6) void cdm_k2(
    const float* __restrict__ emb, const float* __restrict__ wws,
    const float* __restrict__ gws, float* __restrict__ out) {
  const int lane = threadIdx.x & 63;
  const int w = threadIdx.x >> 6;    // j-quarter 0..3
  const int G = __builtin_amdgcn_readfirstlane(blockIdx.x);
  const int r0 = G << 6;             // 64 rows per block, same b
  const int b = r0 >> 9;
  const int i = (r0 + lane) & 511;
  const int jbase = __builtin_amdgcn_readfirstlane(w << 7);

  __shared__ float mv[4][10][64];    // published quarter value-lists
  __shared__ int scnt[64];           // per-row candidate count
  __shared__ float bval[64][17];     // +1 pad (conflict-free readback)
  __shared__ int bidx[64][17];

  // sv2[q] = (c^2)[b] * emb[i] as f2 pairs (per-lane)
  f2 sv2[16];
  {
    const f2* wb = reinterpret_cast<const f2*>(wws + (b << 5));
    const f2* ei = reinterpret_cast<const f2*>(emb + (i << 5));
#pragma unroll
    for (int q = 0; q < 16; ++q) sv2[q] = wb[q] * ei[q];
  }
  const float gateb = gws[b];
  const nf4* eb = reinterpret_cast<const nf4*>(emb);

  // ---- pass 1: branchless top-10 values (med3) over my 128-j quarter ------
  float hv[10];
#pragma unroll
  for (int k = 0; k < 10; ++k) hv[k] = -1e30f;

  for (int t = 0; t < 32; ++t) {
    float a0, a1, a2, a3;
    compute4(eb, sv2, jbase + (t << 2), a0, a1, a2, a3);
    MED3_INSERT(hv, a0);
    MED3_INSERT(hv, a1);
    MED3_INSERT(hv, a2);
    MED3_INSERT(hv, a3);
  }

  // ---- publish + exact global 10th value T --------------------------------
  if (threadIdx.x < 64) scnt[threadIdx.x] = 0;
#pragma unroll
  for (int k = 0; k < 10; ++k) mv[w][k][lane] = hv[k];
  __syncthreads();

  float fv[10];
#pragma unroll
  for (int k = 0; k < 10; ++k) fv[k] = -1e30f;
  for (int h = 0; h < 4; ++h) {
#pragma unroll
    for (int k = 0; k < 10; ++k) {
      float v = mv[h][k][lane];
      MED3_INSERT(fv, v);
    }
  }
  const float T = fv[9];

  // ---- pass 2: recompute identically, collect a >= T ----------------------
  for (int t = 0; t < 32; ++t) {
    const int j0 = jbase + (t << 2);
    float a0, a1, a2, a3;
    compute4(eb, sv2, j0, a0, a1, a2, a3);
    if (a0 >= T) {
      int u = atomicAdd(&scnt[lane], 1);
      if (u < 16) { bval[lane][u] = a0; bidx[lane][u] = j0; }
    }
    if (a1 >= T) {
      int u = atomicAdd(&scnt[lane], 1);
      if (u < 16) { bval[lane][u] = a1; bidx[lane][u] = j0 + 1; }
    }
    if (a2 >= T) {
      int u = atomicAdd(&scnt[lane], 1);
      if (u < 16) { bval[lane][u] = a2; bidx[lane][u] = j0 + 2; }
    }
    if (a3 >= T) {
      int u = atomicAdd(&scnt[lane], 1);
      if (u < 16) { bval[lane][u] = a3; bidx[lane][u] = j0 + 3; }
    }
  }
  __syncthreads();

  // ---- zero-fill my 16 rows now (stores overlap the sort below) -----------
  nf4 z4 = {0.f, 0.f, 0.f, 0.f};
  nf4* zb = reinterpret_cast<nf4*>(out + ((size_t)(r0 + (w << 4)) << 9));
#pragma unroll 8
  for (int k = 0; k < 32; ++k) zb[(k << 6) + lane] = z4;

  // ---- exact final order: u64 key = sortable(v)<<32 | (511-j) -------------
  int n = scnt[lane];
  n = n > 16 ? 16 : n;
  unsigned long long K[10];
#pragma unroll
  for (int k = 0; k < 10; ++k) K[k] = 0ull;
  for (int k = 0; k < n; ++k) {
    float v = bval[lane][k];
    unsigned int bits = __float_as_uint(v);
    unsigned int s = (bits & 0x80000000u) ? ~bits : (bits | 0x80000000u);
    unsigned long long key =
        ((unsigned long long)s << 32) | (unsigned int)(511 - bidx[lane][k]);
    if (key > K[9]) KEY_INSERT(K, key);
  }

  float oval[10];
  int oj[10];
#pragma unroll
  for (int k = 0; k < 10; ++k) {
    unsigned int s = (unsigned int)(K[k] >> 32);
    unsigned int bits = (s & 0x80000000u) ? (s & 0x7fffffffu) : ~s;
    float v = __uint_as_float(bits);
    oval[k] = gateb / (1.f + __expf(-v));
    oj[k] = 511 - (int)(K[k] & 0x1ffu);
  }

  asm volatile("s_waitcnt vmcnt(0)" ::: "memory");
  if ((lane >> 4) == w) {
    float* rb = out + ((size_t)(r0 + lane) << 9);
#pragma unroll
    for (int k = 0; k < 10; ++k) rb[oj[k]] = oval[k];
  }
}

extern "C" void kernel_launch(void* const* d_in, const int* in_sizes, int n_in,
                              void* d_out, int out_size, void* d_ws,
                              size_t ws_size, hipStream_t stream) {
  const float* ctx = (const float*)d_in[0];
  const float* emb = (const float*)d_in[1];
  const float* W1 = (const float*)d_in[2];
  const float* b1 = (const float*)d_in[3];
  const float* W2 = (const float*)d_in[4];
  const float* b2 = (const float*)d_in[5];
  const float* Wg = (const float*)d_in[6];
  const float* bg = (const float*)d_in[7];
  float* out = (float*)d_out;
  float* wws = (float*)d_ws;            // 256*32 floats: c^2
  float* gws = wws + BATCH * EMBED_DIM; // 256 floats: gate

  cdm_k1<<<BATCH, 256, 0, stream>>>(ctx, W1, b1, W2, b2, Wg, bg, wws, gws);
  cdm_k2<<<2048, 256, 0, stream>>>(emb, wws, gws, out);
}